// Round 5
// baseline (304.949 us; speedup 1.0000x reference)
//
#include <hip/hip_runtime.h>
#include <stdint.h>
#include <math.h>

#define BB 2
#define TT 2048
#define CC 1024
#define NH 16
#define HD 64
#define N3 (3*CC)
#define NT (TT/64)      // 32 K-tiles / Q-tiles
#define SPAD 74         // LDS row stride (ushorts): odd dword multiple

typedef __attribute__((ext_vector_type(8))) short bf16x8;
typedef __attribute__((ext_vector_type(4))) float f32x4;

__device__ inline ushort f2bf(float f) {
  uint32_t u = __float_as_uint(f);
  u += 0x7fff + ((u >> 16) & 1);          // RNE
  return (ushort)(u >> 16);
}

// ---------------- cast f32 -> bf16, vectorized ----------------
__global__ __launch_bounds__(256) void cast_bf16_k(const float* __restrict__ in,
                                                   ushort* __restrict__ out, int n)
{
  int i = (blockIdx.x * 256 + threadIdx.x) * 4;
  if (i + 3 < n) {
    float4 v = *(const float4*)(in + i);
    ushort4 o;
    o.x = f2bf(v.x); o.y = f2bf(v.y); o.z = f2bf(v.z); o.w = f2bf(v.w);
    *(ushort4*)(out + i) = o;
  }
}

// ---------------- bf16 MFMA GEMM: C[M,N] = A[M,K] @ W[N,K]^T + bias --------
#define GLDK 40   // 32 + 8 pad (bf16 elems)

template<bool OUT_BF16>
__global__ __launch_bounds__(256) void gemm_mfma(
    const ushort* __restrict__ A, const ushort* __restrict__ W,
    const float* __restrict__ bias, void* __restrict__ Cout,
    int M, int N, int K)
{
  __shared__ ushort As[128 * GLDK];
  __shared__ ushort Ws[128 * GLDK];
  const int tid = threadIdx.x;
  const int lane = tid & 63, wave = tid >> 6;
  const int wr = (wave >> 1) * 64, wc = (wave & 1) * 64;
  const int bm = blockIdx.y * 128, bn = blockIdx.x * 128;
  const int fr = lane & 15, kg = (lane >> 4) * 8, rg = (lane >> 4) * 4;
  const int srow = tid >> 1, skb = (tid & 1) * 16;
  f32x4 acc[4][4];
  #pragma unroll
  for (int m = 0; m < 4; ++m)
    #pragma unroll
    for (int n = 0; n < 4; ++n) acc[m][n] = (f32x4){0.f, 0.f, 0.f, 0.f};

  const ushort* ag = A + (size_t)(bm + srow) * K + skb;
  const ushort* wg = W + (size_t)(bn + srow) * K + skb;
  for (int k0 = 0; k0 < K; k0 += 32) {
    bf16x8 a0 = *(const bf16x8*)(ag + k0);
    bf16x8 a1 = *(const bf16x8*)(ag + k0 + 8);
    bf16x8 w0 = *(const bf16x8*)(wg + k0);
    bf16x8 w1 = *(const bf16x8*)(wg + k0 + 8);
    __syncthreads();
    *(bf16x8*)&As[srow * GLDK + skb]     = a0;
    *(bf16x8*)&As[srow * GLDK + skb + 8] = a1;
    *(bf16x8*)&Ws[srow * GLDK + skb]     = w0;
    *(bf16x8*)&Ws[srow * GLDK + skb + 8] = w1;
    __syncthreads();
    bf16x8 af[4], wf[4];
    #pragma unroll
    for (int m = 0; m < 4; ++m) af[m] = *(const bf16x8*)&As[(wr + m*16 + fr) * GLDK + kg];
    #pragma unroll
    for (int n = 0; n < 4; ++n) wf[n] = *(const bf16x8*)&Ws[(wc + n*16 + fr) * GLDK + kg];
    #pragma unroll
    for (int m = 0; m < 4; ++m)
      #pragma unroll
      for (int n = 0; n < 4; ++n)
        acc[m][n] = __builtin_amdgcn_mfma_f32_16x16x32_bf16(af[m], wf[n], acc[m][n], 0, 0, 0);
  }
  #pragma unroll
  for (int n = 0; n < 4; ++n) {
    const int col = bn + wc + n*16 + fr;
    const float bv = bias[col];
    #pragma unroll
    for (int m = 0; m < 4; ++m)
      #pragma unroll
      for (int r = 0; r < 4; ++r) {
        const int row = bm + wr + m*16 + rg + r;
        const float v = acc[m][n][r] + bv;
        if (OUT_BF16) ((ushort*)Cout)[(size_t)row * N + col] = f2bf(v);
        else          ((float*)Cout)[(size_t)row * N + col]  = v;
      }
  }
}

// ---------------- head-0 scores via MFMA: S = mask(relu(q0 k0^T /8)) -------
__global__ __launch_bounds__(256) void s_scores_mfma(
    const ushort* __restrict__ qkvb, float* __restrict__ SF)
{
  const int jc = blockIdx.x, it = blockIdx.y, b = blockIdx.z;
  if (jc * 8 > it) return;
  __shared__ ushort Qs[64 * SPAD], Ks[64 * SPAD];
  const int tid = threadIdx.x, lane = tid & 63, wave = tid >> 6;
  const int i0 = it * 64;
  const int fr = lane & 15, kg = (lane >> 4) * 8, rg = (lane >> 4) * 4;
  const int srow = tid >> 2, sd = (tid & 3) * 16;
  {
    const ushort* g = qkvb + (size_t)(b*TT + i0 + srow) * N3 + sd;   // head0 q
    bf16x8 v0 = *(const bf16x8*)g, v1 = *(const bf16x8*)(g + 8);
    *(bf16x8*)&Qs[srow*SPAD + sd]     = v0;
    *(bf16x8*)&Qs[srow*SPAD + sd + 8] = v1;
  }
  const int jt1 = min(jc*8 + 7, it);
  for (int jt = jc*8; jt <= jt1; ++jt) {
    const int j0 = jt * 64;
    __syncthreads();
    {
      const ushort* g = qkvb + (size_t)(b*TT + j0 + srow) * N3 + CC + sd;  // head0 k
      bf16x8 v0 = *(const bf16x8*)g, v1 = *(const bf16x8*)(g + 8);
      *(bf16x8*)&Ks[srow*SPAD + sd]     = v0;
      *(bf16x8*)&Ks[srow*SPAD + sd + 8] = v1;
    }
    __syncthreads();
    bf16x8 qf[2];
    #pragma unroll
    for (int kc = 0; kc < 2; ++kc) qf[kc] = *(const bf16x8*)&Qs[(wave*16 + fr)*SPAD + kc*32 + kg];
    #pragma unroll
    for (int n = 0; n < 4; ++n) {
      f32x4 s = (f32x4){0.f, 0.f, 0.f, 0.f};
      #pragma unroll
      for (int kc = 0; kc < 2; ++kc) {
        bf16x8 kf = *(const bf16x8*)&Ks[(n*16 + fr)*SPAD + kc*32 + kg];
        s = __builtin_amdgcn_mfma_f32_16x16x32_bf16(qf[kc], kf, s, 0, 0, 0);
      }
      const int cg = j0 + n*16 + fr;
      #pragma unroll
      for (int r = 0; r < 4; ++r) {
        const int rgg = i0 + wave*16 + rg + r;
        float v = s[r] * 0.125f;
        v = (cg < rgg && cg != 0) ? fmaxf(v, 0.f) : 0.f;   // causal<, col0, diag -> 0
        SF[((size_t)b*TT + rgg)*TT + cg] = v;
      }
    }
  }
}

// ---------------- FF = exclusive column-prefix of S (3-phase scan) ---------
__global__ __launch_bounds__(256) void ff_pass1(const float* __restrict__ SF,
                                                float* __restrict__ part)
{
  const int jg = blockIdx.x & 7, ch = (blockIdx.x >> 3) & 15, b = blockIdx.x >> 7;
  const int j = jg*256 + threadIdx.x;
  const float* p = SF + ((size_t)b*TT + ch*128)*TT + j;
  float s = 0.f;
  for (int i = 0; i < 128; ++i) s += p[(size_t)i*TT];
  part[(b*16 + ch)*TT + j] = s;
}

__global__ __launch_bounds__(256) void ff_pass2(float* __restrict__ SF,
                                                const float* __restrict__ part)
{
  const int jg = blockIdx.x & 7, ch = (blockIdx.x >> 3) & 15, b = blockIdx.x >> 7;
  const int j = jg*256 + threadIdx.x;
  float acc = 0.f;
  for (int c = 0; c < ch; ++c) acc += part[(b*16 + c)*TT + j];
  float* p = SF + ((size_t)b*TT + ch*128)*TT + j;
  for (int i = 0; i < 128; ++i) {
    const float v = p[(size_t)i*TT];
    p[(size_t)i*TT] = acc;
    acc += v;
  }
}

// ---------------- dense flash attention, 1 Q-tile/block, reversed order ----
__device__ __forceinline__ void attn_tile_step(
    const bf16x8 qf[2], const ushort* Ks, const ushort* Vt, ushort* Ps,
    const float* __restrict__ FFb, int i0ws, int j0, bool diag,
    int fr, int kg, int rg,
    f32x4 o[4], float m_run[4], float l_run[4])
{
  // FF loads first: in flight during the QK MFMAs
  float ffv[4][4];
  #pragma unroll
  for (int n = 0; n < 4; ++n)
    #pragma unroll
    for (int r = 0; r < 4; ++r)
      ffv[n][r] = FFb[(size_t)(i0ws + rg + r)*TT + j0 + n*16 + fr];

  float p[4][4];
  float mx[4] = {-INFINITY, -INFINITY, -INFINITY, -INFINITY};
  #pragma unroll
  for (int n = 0; n < 4; ++n) {
    f32x4 s = (f32x4){0.f, 0.f, 0.f, 0.f};
    #pragma unroll
    for (int kc = 0; kc < 2; ++kc) {
      bf16x8 kf = *(const bf16x8*)&Ks[(n*16 + fr)*SPAD + kc*32 + kg];
      s = __builtin_amdgcn_mfma_f32_16x16x32_bf16(qf[kc], kf, s, 0, 0, 0);
    }
    const int cg = j0 + n*16 + fr;
    #pragma unroll
    for (int r = 0; r < 4; ++r) {
      const int rgg = i0ws + rg + r;
      float lg = s[r] * 0.125f - ffv[n][r];
      if (diag) lg = (cg <= rgg) ? lg : -INFINITY;
      p[n][r] = lg;
      mx[r] = fmaxf(mx[r], lg);
    }
  }
  #pragma unroll
  for (int r = 0; r < 4; ++r)
    #pragma unroll
    for (int d = 1; d < 16; d <<= 1) mx[r] = fmaxf(mx[r], __shfl_xor(mx[r], d));
  float scale[4], rs[4];
  #pragma unroll
  for (int r = 0; r < 4; ++r) {
    const float mn = fmaxf(m_run[r], mx[r]);
    scale[r] = __expf(m_run[r] - mn);
    m_run[r] = mn;
    rs[r] = 0.f;
  }
  #pragma unroll
  for (int n = 0; n < 4; ++n)
    #pragma unroll
    for (int r = 0; r < 4; ++r) {
      const float pe = __expf(p[n][r] - m_run[r]);
      p[n][r] = pe;
      rs[r] += pe;
    }
  #pragma unroll
  for (int r = 0; r < 4; ++r) {
    #pragma unroll
    for (int d = 1; d < 16; d <<= 1) rs[r] += __shfl_xor(rs[r], d);
    l_run[r] = l_run[r] * scale[r] + rs[r];
  }
  #pragma unroll
  for (int ds = 0; ds < 4; ++ds)
    #pragma unroll
    for (int r = 0; r < 4; ++r) o[ds][r] *= scale[r];
  #pragma unroll
  for (int n = 0; n < 4; ++n)
    #pragma unroll
    for (int r = 0; r < 4; ++r)
      Ps[(rg + r)*SPAD + n*16 + fr] = f2bf(p[n][r]);   // wave-local rows 0..15
  #pragma unroll
  for (int ds = 0; ds < 4; ++ds)
    #pragma unroll
    for (int kc = 0; kc < 2; ++kc) {
      bf16x8 pf = *(const bf16x8*)&Ps[fr*SPAD + kc*32 + kg];
      bf16x8 vf = *(const bf16x8*)&Vt[(ds*16 + fr)*SPAD + kc*32 + kg];
      o[ds] = __builtin_amdgcn_mfma_f32_16x16x32_bf16(pf, vf, o[ds], 0, 0, 0);
    }
}

__global__ __launch_bounds__(256) void flash_attn3(
    const ushort* __restrict__ qkvb, const float* __restrict__ FF,
    ushort* __restrict__ Yb)
{
  // reversed 1D order: big-it blocks dispatch first, 1-tile blocks fill tail
  const int it = NT - 1 - (blockIdx.x >> 5);
  const int bh = blockIdx.x & 31;
  const int b = bh >> 4, h = bh & 15;
  __shared__ ushort Ks[64*SPAD], Vt[64*SPAD], Ps[4][16*SPAD];
  const int tid = threadIdx.x, lane = tid & 63, wave = tid >> 6;
  const int ws = wave * 16;
  const int fr = lane & 15, kg = (lane >> 4) * 8, rg = (lane >> 4) * 4;
  const float* FFb = FF + (size_t)b*TT*TT;

  bf16x8 qf[2];
  #pragma unroll
  for (int kc = 0; kc < 2; ++kc)
    qf[kc] = *(const bf16x8*)(qkvb + (size_t)(b*TT + it*64 + ws + fr)*N3 + h*HD + kc*32 + kg);

  f32x4 o[4];
  float m_run[4], l_run[4];
  #pragma unroll
  for (int r = 0; r < 4; ++r) {
    m_run[r] = -INFINITY; l_run[r] = 0.f;
    o[r] = (f32x4){0.f,0.f,0.f,0.f};
  }
  const int srow = tid >> 2, sd = (tid & 3) * 16;   // K staging
  const int vrow = tid & 63, vd = (tid >> 6) * 16;  // V staging (transpose)
  const ushort* gk0 = qkvb + (size_t)(b*TT + srow)*N3 + CC + h*HD + sd;
  const ushort* gv0 = qkvb + (size_t)(b*TT + vrow)*N3 + 2*CC + h*HD + vd;

  // T14 async-stage: preload tile 0 into regs
  bf16x8 k0 = *(const bf16x8*)gk0, k1 = *(const bf16x8*)(gk0 + 8);
  bf16x8 u0 = *(const bf16x8*)gv0, u1 = *(const bf16x8*)(gv0 + 8);

  for (int jt = 0; jt <= it; ++jt) {
    __syncthreads();                      // prev tile's LDS reads done
    *(bf16x8*)&Ks[srow*SPAD + sd]     = k0;
    *(bf16x8*)&Ks[srow*SPAD + sd + 8] = k1;
    #pragma unroll
    for (int e = 0; e < 8; ++e) {         // conflict-free transpose write
      Vt[(vd + e)*SPAD + vrow]     = (ushort)u0[e];
      Vt[(vd + 8 + e)*SPAD + vrow] = (ushort)u1[e];
    }
    if (jt < it) {                        // issue next tile's loads now
      const size_t off = (size_t)(jt + 1) * 64 * N3;
      k0 = *(const bf16x8*)(gk0 + off); k1 = *(const bf16x8*)(gk0 + off + 8);
      u0 = *(const bf16x8*)(gv0 + off); u1 = *(const bf16x8*)(gv0 + off + 8);
    }
    __syncthreads();
    attn_tile_step(qf, Ks, Vt, Ps[wave], FFb, it*64 + ws, jt*64, jt == it,
                   fr, kg, rg, o, m_run, l_run);
  }
  #pragma unroll
  for (int ds = 0; ds < 4; ++ds)
    #pragma unroll
    for (int r = 0; r < 4; ++r) {
      const int dg = h*HD + ds*16 + fr;
      Yb[(size_t)(b*TT + it*64 + ws + rg + r)*CC + dg] = f2bf(o[ds][r] / l_run[r]);
    }
}

// ---------------------------------------------------------------------------
extern "C" void kernel_launch(void* const* d_in, const int* in_sizes, int n_in,
                              void* d_out, int out_size, void* d_ws, size_t ws_size,
                              hipStream_t stream) {
  const float* x      = (const float*)d_in[0];
  const float* w_attn = (const float*)d_in[1];
  const float* b_attn = (const float*)d_in[2];
  const float* w_proj = (const float*)d_in[3];
  const float* b_proj = (const float*)d_in[4];
  float* out = (float*)d_out;

  // workspace layout (~118 MB)
  ushort* xb   = (ushort*)d_ws;                         // B*T*C bf16
  ushort* wab  = xb   + (size_t)BB*TT*CC;               // 3C*C bf16
  ushort* wpb  = wab  + (size_t)N3*CC;                  // C*C bf16
  ushort* qkvb = wpb  + (size_t)CC*CC;                  // B*T*3C bf16
  ushort* Yb   = qkvb + (size_t)BB*TT*N3;               // B*T*C bf16
  float*  SF   = (float*)(Yb + (size_t)BB*TT*CC);       // B*T*T f32 (S then FF)
  float*  part = SF + (size_t)BB*TT*TT;                 // B*16*T f32

  cast_bf16_k<<<(BB*TT*CC/4 + 255)/256, 256, 0, stream>>>(x, xb, BB*TT*CC);
  cast_bf16_k<<<(N3*CC/4 + 255)/256, 256, 0, stream>>>(w_attn, wab, N3*CC);
  cast_bf16_k<<<(CC*CC/4 + 255)/256, 256, 0, stream>>>(w_proj, wpb, CC*CC);

  gemm_mfma<true><<<dim3(N3/128, (BB*TT)/128), 256, 0, stream>>>(
      xb, wab, b_attn, (void*)qkvb, BB*TT, N3, CC);

  hipMemsetAsync(SF, 0, (size_t)BB*TT*TT*sizeof(float), stream);
  s_scores_mfma<<<dim3(4, TT/64, BB), 256, 0, stream>>>(qkvb, SF);

  ff_pass1<<<256, 256, 0, stream>>>(SF, part);
  ff_pass2<<<256, 256, 0, stream>>>(SF, part);

  flash_attn3<<<NT*BB*NH, 256, 0, stream>>>(qkvb, SF, Yb);

  gemm_mfma<false><<<dim3(CC/128, (BB*TT)/128), 256, 0, stream>>>(
      Yb, wpb, b_proj, (void*)out, BB*TT, CC, CC);
}

// Round 6
// 253.101 us; speedup vs baseline: 1.2049x; 1.2049x over previous
//
#include <hip/hip_runtime.h>
#include <stdint.h>
#include <math.h>

#define BB 2
#define TT 2048
#define CC 1024
#define NH 16
#define HD 64
#define N3 (3*CC)
#define NT (TT/64)
#define SPAD 74         // LDS row stride for 16x16-path kernels

typedef __attribute__((ext_vector_type(8)))  short bf16x8;
typedef __attribute__((ext_vector_type(4)))  float f32x4;
typedef __attribute__((ext_vector_type(16))) float f32x16;

__device__ inline ushort f2bf(float f) {
  uint32_t u = __float_as_uint(f);
  u += 0x7fff + ((u >> 16) & 1);          // RNE
  return (ushort)(u >> 16);
}

__device__ inline uint32_t cvt_pk_bf16(float lo, float hi_) {
  uint32_t r;
  asm("v_cvt_pk_bf16_f32 %0, %1, %2" : "=v"(r) : "v"(lo), "v"(hi_));
  return r;
}

typedef union { uint32_t u[4]; bf16x8 v; } pack4_t;

// ---------------- cast f32 -> bf16, vectorized ----------------
__global__ __launch_bounds__(256) void cast_bf16_k(const float* __restrict__ in,
                                                   ushort* __restrict__ out, int n)
{
  int i = (blockIdx.x * 256 + threadIdx.x) * 4;
  if (i + 3 < n) {
    float4 v = *(const float4*)(in + i);
    ushort4 o;
    o.x = f2bf(v.x); o.y = f2bf(v.y); o.z = f2bf(v.z); o.w = f2bf(v.w);
    *(ushort4*)(out + i) = o;
  }
}

// ---------------- bf16 MFMA GEMM: C[M,N] = A[M,K] @ W[N,K]^T + bias --------
#define GLDK 40

template<bool OUT_BF16>
__global__ __launch_bounds__(256) void gemm_mfma(
    const ushort* __restrict__ A, const ushort* __restrict__ W,
    const float* __restrict__ bias, void* __restrict__ Cout,
    int M, int N, int K)
{
  __shared__ ushort As[128 * GLDK];
  __shared__ ushort Ws[128 * GLDK];
  const int tid = threadIdx.x;
  const int lane = tid & 63, wave = tid >> 6;
  const int wr = (wave >> 1) * 64, wc = (wave & 1) * 64;
  const int bm = blockIdx.y * 128, bn = blockIdx.x * 128;
  const int fr = lane & 15, kg = (lane >> 4) * 8, rg = (lane >> 4) * 4;
  const int srow = tid >> 1, skb = (tid & 1) * 16;
  f32x4 acc[4][4];
  #pragma unroll
  for (int i=0;i<4;++i)
    #pragma unroll
    for (int j=0;j<4;++j) acc[i][j]=(f32x4){0.f,0.f,0.f,0.f};

  const ushort* ag = A + (size_t)(bm + srow) * K + skb;
  const ushort* wg = W + (size_t)(bn + srow) * K + skb;
  for (int k0 = 0; k0 < K; k0 += 32) {
    bf16x8 a0 = *(const bf16x8*)(ag + k0);
    bf16x8 a1 = *(const bf16x8*)(ag + k0 + 8);
    bf16x8 w0 = *(const bf16x8*)(wg + k0);
    bf16x8 w1 = *(const bf16x8*)(wg + k0 + 8);
    __syncthreads();
    *(bf16x8*)&As[srow * GLDK + skb]     = a0;
    *(bf16x8*)&As[srow * GLDK + skb + 8] = a1;
    *(bf16x8*)&Ws[srow * GLDK + skb]     = w0;
    *(bf16x8*)&Ws[srow * GLDK + skb + 8] = w1;
    __syncthreads();
    bf16x8 af[4], wf[4];
    #pragma unroll
    for (int m = 0; m < 4; ++m) af[m] = *(const bf16x8*)&As[(wr + m*16 + fr) * GLDK + kg];
    #pragma unroll
    for (int n = 0; n < 4; ++n) wf[n] = *(const bf16x8*)&Ws[(wc + n*16 + fr) * GLDK + kg];
    #pragma unroll
    for (int m = 0; m < 4; ++m)
      #pragma unroll
      for (int n = 0; n < 4; ++n)
        acc[m][n] = __builtin_amdgcn_mfma_f32_16x16x32_bf16(af[m], wf[n], acc[m][n], 0, 0, 0);
  }
  #pragma unroll
  for (int n = 0; n < 4; ++n) {
    const int col = bn + wc + n*16 + fr;
    const float bv = bias[col];
    #pragma unroll
    for (int m = 0; m < 4; ++m)
      #pragma unroll
      for (int r = 0; r < 4; ++r) {
        const int row = bm + wr + m*16 + rg + r;
        const float v = acc[m][n][r] + bv;
        if (OUT_BF16) ((ushort*)Cout)[(size_t)row * N + col] = f2bf(v);
        else          ((float*)Cout)[(size_t)row * N + col]  = v;
      }
  }
}

// ---------------- head-0 scores via MFMA: S = mask(relu(q0 k0^T /8)) -------
__global__ __launch_bounds__(256) void s_scores_mfma(
    const ushort* __restrict__ qkvb, float* __restrict__ SF)
{
  const int jc = blockIdx.x, it = blockIdx.y, b = blockIdx.z;
  if (jc * 8 > it) return;
  __shared__ ushort Qs[64 * SPAD], Ks[64 * SPAD];
  const int tid = threadIdx.x, lane = tid & 63, wave = tid >> 6;
  const int i0 = it * 64;
  const int fr = lane & 15, kg = (lane >> 4) * 8, rg = (lane >> 4) * 4;
  const int srow = tid >> 2, sd = (tid & 3) * 16;
  {
    const ushort* g = qkvb + (size_t)(b*TT + i0 + srow) * N3 + sd;
    bf16x8 v0 = *(const bf16x8*)g, v1 = *(const bf16x8*)(g + 8);
    *(bf16x8*)&Qs[srow*SPAD + sd]     = v0;
    *(bf16x8*)&Qs[srow*SPAD + sd + 8] = v1;
  }
  const int jt1 = min(jc*8 + 7, it);
  for (int jt = jc*8; jt <= jt1; ++jt) {
    const int j0 = jt * 64;
    __syncthreads();
    {
      const ushort* g = qkvb + (size_t)(b*TT + j0 + srow) * N3 + CC + sd;
      bf16x8 v0 = *(const bf16x8*)g, v1 = *(const bf16x8*)(g + 8);
      *(bf16x8*)&Ks[srow*SPAD + sd]     = v0;
      *(bf16x8*)&Ks[srow*SPAD + sd + 8] = v1;
    }
    __syncthreads();
    bf16x8 qf[2];
    #pragma unroll
    for (int kc = 0; kc < 2; ++kc) qf[kc] = *(const bf16x8*)&Qs[(wave*16 + fr)*SPAD + kc*32 + kg];
    #pragma unroll
    for (int n = 0; n < 4; ++n) {
      f32x4 s = (f32x4){0.f, 0.f, 0.f, 0.f};
      #pragma unroll
      for (int kc = 0; kc < 2; ++kc) {
        bf16x8 kf = *(const bf16x8*)&Ks[(n*16 + fr)*SPAD + kc*32 + kg];
        s = __builtin_amdgcn_mfma_f32_16x16x32_bf16(qf[kc], kf, s, 0, 0, 0);
      }
      const int cg = j0 + n*16 + fr;
      #pragma unroll
      for (int r = 0; r < 4; ++r) {
        const int rgg = i0 + wave*16 + rg + r;
        float v = s[r] * 0.125f;
        v = (cg < rgg && cg != 0) ? fmaxf(v, 0.f) : 0.f;
        SF[((size_t)b*TT + rgg)*TT + cg] = v;
      }
    }
  }
}

// ---------------- FF = exclusive column-prefix of S (3-phase scan) ---------
__global__ __launch_bounds__(256) void ff_pass1(const float* __restrict__ SF,
                                                float* __restrict__ part)
{
  const int jg = blockIdx.x & 7, ch = (blockIdx.x >> 3) & 15, b = blockIdx.x >> 7;
  const int j = jg*256 + threadIdx.x;
  const float* p = SF + ((size_t)b*TT + ch*128)*TT + j;
  float s = 0.f;
  for (int i = 0; i < 128; ++i) s += p[(size_t)i*TT];
  part[(b*16 + ch)*TT + j] = s;
}

__global__ __launch_bounds__(256) void ff_pass2(float* __restrict__ SF,
                                                const float* __restrict__ part)
{
  const int jg = blockIdx.x & 7, ch = (blockIdx.x >> 3) & 15, b = blockIdx.x >> 7;
  const int j = jg*256 + threadIdx.x;
  float acc = 0.f;
  for (int c = 0; c < ch; ++c) acc += part[(b*16 + c)*TT + j];
  float* p = SF + ((size_t)b*TT + ch*128)*TT + j;
  for (int i = 0; i < 128; ++i) {
    const float v = p[(size_t)i*TT];
    p[(size_t)i*TT] = acc;
    acc += v;
  }
}

// ---------------- flash attention, swapped QK^T, in-register softmax -------
// block = 4 waves x 32 q-rows = 128 rows; 32x32x16 MFMA; V via LDS transpose.
// S^T = mfma(K, Q): lane q = lane&31; j(reg) = (reg&3)+8*(reg>>2)+4*(lane>>5).
__global__ __launch_bounds__(256) void flash_attn4(
    const ushort* __restrict__ qkvb, const float* __restrict__ FF,
    ushort* __restrict__ Yb)
{
  const int bx = blockIdx.x;                 // i-block of 128 rows (0..15)
  const int b = blockIdx.y >> 4, h = blockIdx.y & 15;
  const int tid = threadIdx.x, lane = tid & 63, wv = tid >> 6;
  const int hi = lane >> 5, lq = lane & 31;
  const int i0w = bx*128 + wv*32;            // wave's first q-row
  const int qg  = i0w + lq;                  // lane's q-row (global)
  __shared__ __align__(16) ushort Vt[64][72]; // [d][j], 144B row: 16B-aligned

  // Q B-fragments: Q[qg][dc*16 + hi*8 + e]
  bf16x8 qf[4];
  const ushort* qrow = qkvb + (size_t)(b*TT + qg)*N3 + h*HD + hi*8;
  #pragma unroll
  for (int dc = 0; dc < 4; ++dc) qf[dc] = *(const bf16x8*)(qrow + dc*16);

  f32x16 o0, o1;
  #pragma unroll
  for (int r = 0; r < 16; ++r) { o0[r] = 0.f; o1[r] = 0.f; }
  float m_run = -INFINITY, l_run = 0.f;

  const int jtmax = 2*bx + 1;
  const int vrow = tid & 63, vd = (tid >> 6) * 16;   // V staging role
  const ushort* gv0 = qkvb + (size_t)(b*TT + vrow)*N3 + 2*CC + h*HD + vd;
  bf16x8 u0 = *(const bf16x8*)gv0, u1 = *(const bf16x8*)(gv0 + 8);

  for (int jt = 0; jt <= jtmax; ++jt) {
    __syncthreads();
    #pragma unroll
    for (int e = 0; e < 8; ++e) {            // transpose write, conflict-free
      Vt[vd + e][vrow]     = (ushort)u0[e];
      Vt[vd + 8 + e][vrow] = (ushort)u1[e];
    }
    __syncthreads();
    if (jt < jtmax) {                        // prefetch next V tile
      const ushort* gv = gv0 + (size_t)(jt + 1)*64*N3;
      u0 = *(const bf16x8*)gv; u1 = *(const bf16x8*)(gv + 8);
    }
    const int j0t = jt*64;
    if (j0t > i0w + 31) continue;            // wave-uniform skip (barriers done)

    #pragma unroll
    for (int jsub = 0; jsub < 2; ++jsub) {
      const int j0s = j0t + jsub*32;
      if (j0s > i0w + 31) continue;          // wave-uniform

      // QK^T swapped: st[j, q], K A-frags direct from global
      f32x16 st;
      #pragma unroll
      for (int r = 0; r < 16; ++r) st[r] = 0.f;
      const ushort* kr = qkvb + (size_t)(b*TT + j0s + lq)*N3 + CC + h*HD + hi*8;
      #pragma unroll
      for (int dc = 0; dc < 4; ++dc) {
        bf16x8 kf = *(const bf16x8*)(kr + dc*16);
        st = __builtin_amdgcn_mfma_f32_32x32x16_bf16(kf, qf[dc], st, 0, 0, 0);
      }
      // FF bias: 4x float4 per lane (j = j0s + 8g + 4hi + m)
      float ffv[16];
      const float* ffp = FF + (size_t)(b*TT + qg)*TT + j0s + hi*4;
      #pragma unroll
      for (int g = 0; g < 4; ++g) {
        float4 t = *(const float4*)(ffp + 8*g);
        ffv[4*g]=t.x; ffv[4*g+1]=t.y; ffv[4*g+2]=t.z; ffv[4*g+3]=t.w;
      }
      // logits + row max (in-lane 16 + one cross-half swap)
      float lg[16];
      float pmax = -INFINITY;
      const bool need_mask = (j0s + 31 > i0w);
      #pragma unroll
      for (int r = 0; r < 16; ++r) {
        float v = st[r]*0.125f - ffv[r];
        if (need_mask) {
          const int j = j0s + (r&3) + 8*(r>>2) + 4*hi;
          v = (j <= qg) ? v : -INFINITY;
        }
        lg[r] = v;
        pmax = fmaxf(pmax, v);
      }
      pmax = fmaxf(pmax, __shfl_xor(pmax, 32));
      // T13 defer-max: rescale only when the row max actually grows
      if (!__all(pmax <= m_run)) {
        const float mn = fmaxf(m_run, pmax);
        const float sc = __expf(m_run - mn);   // first tile: exp(-inf)=0
        m_run = mn;
        l_run *= sc;
        #pragma unroll
        for (int r = 0; r < 16; ++r) {
          const float s0 = __shfl(sc, (r&3) + 8*(r>>2) + 4*hi);
          o0[r] *= s0; o1[r] *= s0;
        }
      }
      float rs = 0.f;
      #pragma unroll
      for (int r = 0; r < 16; ++r) {
        const float pe = __expf(lg[r] - m_run);
        lg[r] = pe;
        rs += pe;
      }
      rs += __shfl_xor(rs, 32);
      l_run += rs;
      // pack P into A-fragments: pairs (j, j+1); own j = 8g + 4hi + m
      uint32_t P8[8], Q8[8];
      #pragma unroll
      for (int g = 0; g < 4; ++g) {
        P8[2*g]   = cvt_pk_bf16(lg[4*g],   lg[4*g+1]);
        P8[2*g+1] = cvt_pk_bf16(lg[4*g+2], lg[4*g+3]);
      }
      #pragma unroll
      for (int k = 0; k < 8; ++k) Q8[k] = (uint32_t)__shfl_xor((int)P8[k], 32);
      #pragma unroll
      for (int mm = 0; mm < 2; ++mm) {
        pack4_t pk;
        pk.u[0] = hi ? Q8[4*mm+2] : P8[4*mm];
        pk.u[1] = hi ? Q8[4*mm+3] : P8[4*mm+1];
        pk.u[2] = hi ? P8[4*mm+2] : Q8[4*mm];
        pk.u[3] = hi ? P8[4*mm+3] : Q8[4*mm+1];
        const bf16x8 pa = pk.v;
        const bf16x8 v0 = *(const bf16x8*)&Vt[lq]     [jsub*32 + mm*16 + hi*8];
        const bf16x8 v1 = *(const bf16x8*)&Vt[32 + lq][jsub*32 + mm*16 + hi*8];
        o0 = __builtin_amdgcn_mfma_f32_32x32x16_bf16(pa, v0, o0, 0, 0, 0);
        o1 = __builtin_amdgcn_mfma_f32_32x32x16_bf16(pa, v1, o1, 0, 0, 0);
      }
    }
  }
  // epilogue: O[q = (r&3)+8*(r>>2)+4*hi][d = d0 + lq]
  const float invl = 1.0f / l_run;
  #pragma unroll
  for (int r = 0; r < 16; ++r) {
    const int qm = (r&3) + 8*(r>>2) + 4*hi;
    const float il = __shfl(invl, qm);
    const size_t row = (size_t)(b*TT + i0w + qm)*CC + h*HD;
    Yb[row + lq]      = f2bf(o0[r] * il);
    Yb[row + 32 + lq] = f2bf(o1[r] * il);
  }
}

// ---------------------------------------------------------------------------
extern "C" void kernel_launch(void* const* d_in, const int* in_sizes, int n_in,
                              void* d_out, int out_size, void* d_ws, size_t ws_size,
                              hipStream_t stream) {
  const float* x      = (const float*)d_in[0];
  const float* w_attn = (const float*)d_in[1];
  const float* b_attn = (const float*)d_in[2];
  const float* w_proj = (const float*)d_in[3];
  const float* b_proj = (const float*)d_in[4];
  float* out = (float*)d_out;

  ushort* xb   = (ushort*)d_ws;                         // B*T*C bf16
  ushort* wab  = xb   + (size_t)BB*TT*CC;               // 3C*C bf16
  ushort* wpb  = wab  + (size_t)N3*CC;                  // C*C bf16
  ushort* qkvb = wpb  + (size_t)CC*CC;                  // B*T*3C bf16
  ushort* Yb   = qkvb + (size_t)BB*TT*N3;               // B*T*C bf16
  float*  SF   = (float*)(Yb + (size_t)BB*TT*CC);       // B*T*T f32 (S then FF)
  float*  part = SF + (size_t)BB*TT*TT;                 // B*16*T f32

  cast_bf16_k<<<(BB*TT*CC/4 + 255)/256, 256, 0, stream>>>(x, xb, BB*TT*CC);
  cast_bf16_k<<<(N3*CC/4 + 255)/256, 256, 0, stream>>>(w_attn, wab, N3*CC);
  cast_bf16_k<<<(CC*CC/4 + 255)/256, 256, 0, stream>>>(w_proj, wpb, CC*CC);

  gemm_mfma<true><<<dim3(N3/128, (BB*TT)/128), 256, 0, stream>>>(
      xb, wab, b_attn, (void*)qkvb, BB*TT, N3, CC);

  hipMemsetAsync(SF, 0, (size_t)BB*TT*TT*sizeof(float), stream);
  s_scores_mfma<<<dim3(4, TT/64, BB), 256, 0, stream>>>(qkvb, SF);

  ff_pass1<<<256, 256, 0, stream>>>(SF, part);
  ff_pass2<<<256, 256, 0, stream>>>(SF, part);

  flash_attn4<<<dim3(TT/128, BB*NH), 256, 0, stream>>>(qkvb, SF, Yb);

  gemm_mfma<false><<<dim3(CC/128, (BB*TT)/128), 256, 0, stream>>>(
      Yb, wpb, b_proj, (void*)out, BB*TT, CC, CC);
}